// Round 8
// baseline (44.080 us; speedup 1.0000x reference)
//
#include <hip/hip_runtime.h>

// Depthwise conv1d along L, K=25, replicate padding, + scalar bias.
// x: [B=32, L=2048, C=512] f32 -> out same shape.
//
// R7: last traffic lever. TL=256 outputs x 32 channels per block:
// halo ratio 280/256 = 1.09x (was 1.19x at TL=128). LDS 35 KB -> still
// 4 blocks/CU. Same R4/R6 skeleton: stage-all (global_load_lds w=16) ->
// syncthreads -> compute from LDS -> NT store. This is the decisive
// experiment: null result => fabric-bound at mixed r+w ceiling => roofline.

typedef float f32x4 __attribute__((ext_vector_type(4)));

constexpr int K     = 25;
constexpr int HALF  = 12;
constexpr int BB    = 32;
constexpr int LL    = 2048;
constexpr int CC    = 512;
constexpr int QCH   = 32;               // channels per block
constexpr int QC4   = QCH / 4;          // 8 f32x4 per row segment
constexpr int TL    = 256;              // L-outputs per block
constexpr int NROWS = TL + K - 1;       // 280 staged rows
constexpr int NGRP  = NROWS / 8;        // 35 gll16 groups (1KB = 8 rows each)
constexpr int NQ    = CC / QCH;         // 16
constexpr int NT    = LL / TL;          // 8
constexpr int NBLK  = BB * NQ * NT;     // 4096

__device__ inline void gll16(const float* g, float* l) {
    __builtin_amdgcn_global_load_lds(
        (const __attribute__((address_space(1))) void*)g,
        (__attribute__((address_space(3))) void*)l, 16, 0, 0);
}

__global__ __launch_bounds__(256) void conv1d_dw_kernel(
    const float* __restrict__ x,
    const float* __restrict__ w,
    const float* __restrict__ bias_p,
    float* __restrict__ out)
{
    __shared__ float lds[NROWS * QCH];      // 35840 B

    // XCD-aware swizzle; adjacent lbid = adjacent L-tile of same (b,qc)
    // so halo lines are L2-warm on the same XCD.
    const int bid  = blockIdx.x;
    const int lbid = (bid & 7) * (NBLK >> 3) + (bid >> 3);

    const int lt = lbid & (NT - 1);          // 0..7   L-tile
    const int qc = (lbid >> 3) & (NQ - 1);   // 0..15  channel slice
    const int b  = lbid >> 7;                // 0..31

    const int tid  = threadIdx.x;
    const int wv   = tid >> 6;               // 0..3
    const int lane = tid & 63;

    const int Lbase = lt * TL;
    const float* xq = x   + (size_t)b * LL * CC + qc * QCH;
    float*       oq = out + (size_t)b * LL * CC + qc * QCH;

    // ---- stage 280 rows x 128 B (35 x 1KB gll16 per block) ----
#pragma unroll
    for (int i = 0; i < 9; ++i) {
        const int g = wv + 4 * i;                     // wave-uniform
        if (g < NGRP) {
            const int v  = g * 8 + (lane >> 3);       // staged row 0..279
            const int li = max(0, min(LL - 1, Lbase + v - HALF));
            gll16(xq + (size_t)li * CC + (lane & 7) * 4,
                  lds + (size_t)g * 8 * QCH);         // linear dest, +lane*16
        }
    }

    float wr[K];
#pragma unroll
    for (int k = 0; k < K; ++k) wr[k] = w[k];         // wave-uniform -> SGPR
    const float bias = bias_p[0];

    __syncthreads();                                  // vmcnt(0) drain here

    // ---- compute: thread = (lgrp = tid>>3 -> 8 l-outputs, c4 = tid&7) ----
    const int lgrp = tid >> 3;               // 0..31
    const int c4   = tid & 7;                // f32x4 column

    f32x4 acc[8];
#pragma unroll
    for (int j = 0; j < 8; ++j) acc[j] = (f32x4){bias, bias, bias, bias};

    const f32x4* ldsv = reinterpret_cast<const f32x4*>(lds);
#pragma unroll
    for (int rr = 0; rr < 32; ++rr) {
        const f32x4 rv = ldsv[(size_t)(lgrp * 8 + rr) * QC4 + c4];
#pragma unroll
        for (int j = 0; j < 8; ++j) {
            const int k = rr - j;            // compile-time per (rr,j)
            if (k >= 0 && k < K) acc[j] += wr[k] * rv;
        }
    }

    const int l0 = Lbase + lgrp * 8;
#pragma unroll
    for (int j = 0; j < 8; ++j)
        __builtin_nontemporal_store(acc[j],
            reinterpret_cast<f32x4*>(oq + (size_t)(l0 + j) * CC) + c4);
}

extern "C" void kernel_launch(void* const* d_in, const int* in_sizes, int n_in,
                              void* d_out, int out_size, void* d_ws, size_t ws_size,
                              hipStream_t stream) {
    const float* x  = (const float*)d_in[0];
    const float* w  = (const float*)d_in[1];
    const float* bp = (const float*)d_in[2];
    float* out      = (float*)d_out;

    conv1d_dw_kernel<<<NBLK, 256, 0, stream>>>(x, w, bp, out);
}